// Round 9
// baseline (338.575 us; speedup 1.0000x reference)
//
#include <hip/hip_runtime.h>
#include <hip/hip_bf16.h>
#include <stdint.h>

#define DEVI __device__ __forceinline__

using bf16x8 = __attribute__((ext_vector_type(8))) short;
using f32x4  = __attribute__((ext_vector_type(4))) float;
using f16x4  = __attribute__((ext_vector_type(4))) _Float16;
using f16x8  = __attribute__((ext_vector_type(8))) _Float16;

static constexpr int Bc = 4;
static constexpr int Tc = 2048;
static constexpr int Dc = 1024;
static constexpr int Hc = 16;
static constexpr int HDc = 64;
// 1/sqrt(512) * log2(e), folded into Q so softmax uses exp2 directly
#define QSCALE 0.06375788883274286f

#if __has_builtin(__builtin_amdgcn_exp2f)
#define EXP2F __builtin_amdgcn_exp2f
#else
#define EXP2F exp2f
#endif

typedef const unsigned int __attribute__((address_space(1)))* gas1_t;
typedef unsigned int __attribute__((address_space(3)))* las3_t;

DEVI void gld16(const void* g, void* l)
{
    __builtin_amdgcn_global_load_lds((gas1_t)(uintptr_t)g, (las3_t)(uintptr_t)l, 16, 0, 0);
}

// ---------------- fused prep kernel ----------------
// One launch, block-range partitioned (saves 3 kernel launch gaps):
//   blocks [0,2048):     x fp32 -> bf16 (64B/thread, block-strided)
//   blocks [2048,2816):  W_attn [K][N] fp32 -> Wqt [N][K] bf16 (64x64 tiles)
//   blocks [2816,3072):  W_proj -> Wpt
//   blocks [3072,3584):  RoPE sin/cos tables

DEVI void transpose_tile(const float* __restrict__ W, __hip_bfloat16* __restrict__ Wt,
                         int K, int N, int n0, int k0, float (*tile)[65], int tid)
{
    const int tx = tid & 15, ty = tid >> 4;   // 16 x 16
#pragma unroll
    for (int i2 = 0; i2 < 4; i2++) {
        const int k = ty + 16 * i2;
        float4 v = *(const float4*)&W[(size_t)(k0 + k) * N + n0 + tx * 4];
        tile[tx * 4 + 0][k] = v.x;
        tile[tx * 4 + 1][k] = v.y;
        tile[tx * 4 + 2][k] = v.z;
        tile[tx * 4 + 3][k] = v.w;
    }
    __syncthreads();
#pragma unroll
    for (int i2 = 0; i2 < 4; i2++) {
        const int n = ty + 16 * i2;
        union { __hip_bfloat16 h[4]; ushort4 u4; } cv;
#pragma unroll
        for (int c = 0; c < 4; c++)
            cv.h[c] = (__hip_bfloat16)tile[n][tx * 4 + c];
        *(ushort4*)&Wt[(size_t)(n0 + n) * K + k0 + tx * 4] = cv.u4;
    }
}

__global__ __launch_bounds__(256) void prep_kernel(
    const float4* __restrict__ x, ushort4* __restrict__ xb,
    const float* __restrict__ W_attn, __hip_bfloat16* __restrict__ Wqt,
    const float* __restrict__ W_proj, __hip_bfloat16* __restrict__ Wpt,
    float* __restrict__ sinT, float* __restrict__ cosT)
{
    __shared__ float tile[64][65];
    const int bid = blockIdx.x, tid = threadIdx.x;
    if (bid < 2048) {
        const int base = bid * 1024 + tid;
#pragma unroll
        for (int u = 0; u < 4; u++) {
            const int i = base + u * 256;
            float4 v = x[i];
            union { __hip_bfloat16 h[4]; ushort4 u4; } cv;
            cv.h[0] = __float2bfloat16(v.x);
            cv.h[1] = __float2bfloat16(v.y);
            cv.h[2] = __float2bfloat16(v.z);
            cv.h[3] = __float2bfloat16(v.w);
            xb[i] = cv.u4;
        }
    } else if (bid < 2816) {
        const int b2 = bid - 2048;                    // grid was (48, 16)
        transpose_tile(W_attn, Wqt, Dc, 3 * Dc, (b2 % 48) * 64, (b2 / 48) * 64, tile, tid);
    } else if (bid < 3072) {
        const int b3 = bid - 2816;                    // grid was (16, 16)
        transpose_tile(W_proj, Wpt, Dc, Dc, (b3 % 16) * 64, (b3 / 16) * 64, tile, tid);
    } else {
        const int i = (bid - 3072) * 256 + tid;       // Tc*64 total
        const int t = i >> 6, dim = i & 63;
        const int p = dim >> 1;
        float theta = powf(1000.f, -2.f * (float)(p + 1) / 64.f);
        float arg = (float)(t + 1) * theta;
        sinT[i] = sinf(arg);
        cosT[i] = cosf(arg);
    }
}

// ---------------- GEMM: 128x128 tile, TRANSPOSED C-orientation ----------------
// A-operand = weight rows (n), B-operand = x rows (m) -> D[n][m].
// K-loop: m97 structure — SINGLE-buffered LDS (32 KB -> ~4 blocks/CU), plain
// drain loop {stage -> vmcnt(0) -> barrier -> compute -> barrier}. Pipelining
// comes from implicit wave-level overlap across co-resident blocks (m114).
// (Round-8 A/B: this beats the 64 KB explicit dbuf 77.8 vs 79 us.)
// LDS octet XOR-swizzle (pre-swizzled GLOBAL source + swizzled read; LDS linear,
// rule #21) kills the 16-way ds_read_b128 bank conflict.
// MODE 0: QKV epilogue (RoPE; Q scaled; K dim-swizzled; V -> f16 transposed+permuted)
// MODE 1: proj epilogue (fp32 out + bias)

template <int MODE>
__global__ __launch_bounds__(256, 4) void gemm128(
    const __hip_bfloat16* __restrict__ A, const __hip_bfloat16* __restrict__ Bt,
    const float* __restrict__ bias, int M, int N, int K,
    const float* __restrict__ sinT, const float* __restrict__ cosT,
    __hip_bfloat16* __restrict__ Qb, __hip_bfloat16* __restrict__ Kb,
    _Float16* __restrict__ Vb, float* __restrict__ Cout)
{
    __shared__ __align__(16) __hip_bfloat16 sA[128 * 64];
    __shared__ __align__(16) __hip_bfloat16 sB[128 * 64];
    const int tid = threadIdx.x;
    const int wave = tid >> 6, lane = tid & 63;
    const int qd = lane >> 4, lm = lane & 15;
    const int wm = (wave >> 1) * 64, wn = (wave & 1) * 64;
    const int tileM = blockIdx.y * 128, tileN = blockIdx.x * 128;

    const int srow = tid >> 3;                      // 0..31 (staged row within chunk)
    const int socc = (tid & 7) ^ (srow & 7);        // swizzled source octet

    f32x4 acc[4][4];                    // [a: n-block][b: m-block]
#pragma unroll
    for (int i = 0; i < 4; i++)
#pragma unroll
        for (int j = 0; j < 4; j++)
            acc[i][j] = (f32x4){0.f, 0.f, 0.f, 0.f};

    // LDS[row][o] holds global octet o ^ (row&7); rows stay linear for gld16
    const __hip_bfloat16* pa = A + (size_t)(tileM + srow) * K + socc * 8;
    const __hip_bfloat16* pb = Bt + (size_t)(tileN + srow) * K + socc * 8;

    auto stageT = [&](int k0) {
#pragma unroll
        for (int it = 0; it < 4; it++) {
            gld16(pa + (size_t)(it * 32) * K + k0, &sA[it * 2048 + wave * 512]);
            gld16(pb + (size_t)(it * 32) * K + k0, &sB[it * 2048 + wave * 512]);
        }
    };

    const int swl = (lm & 7) << 3;      // read-side octet swizzle (row&7 == lm&7)
    const int nk = K / 64;
    for (int kt = 0; kt < nk; kt++) {
        stageT(kt * 64);
        __builtin_amdgcn_s_waitcnt(0xF70);       // vmcnt(0): tile kt landed
        __builtin_amdgcn_s_barrier();            // all waves' loads landed

#pragma unroll
        for (int ks = 0; ks < 2; ks++) {
            bf16x8 wf[4], xf[4];
#pragma unroll
            for (int a = 0; a < 4; a++)
                wf[a] = *(const bf16x8*)&sB[(wn + a * 16 + lm) * 64
                                            + ((ks * 32 + qd * 8) ^ swl)];
#pragma unroll
            for (int b = 0; b < 4; b++)
                xf[b] = *(const bf16x8*)&sA[(wm + b * 16 + lm) * 64
                                            + ((ks * 32 + qd * 8) ^ swl)];
#pragma unroll
            for (int a = 0; a < 4; a++)
#pragma unroll
                for (int b = 0; b < 4; b++)
                    acc[a][b] = __builtin_amdgcn_mfma_f32_16x16x32_bf16(
                        wf[a], xf[b], acc[a][b], 0, 0, 0);
        }
        if (kt + 1 < nk)
            __builtin_amdgcn_s_barrier();        // reads done before next overwrite
    }

    if constexpr (MODE == 0) {
        const int sec = tileN >> 10;                    // q/k/v section, block-uniform
        const int h = ((tileN + wn) & 1023) >> 6;       // head, wave-uniform
#pragma unroll
        for (int a = 0; a < 4; a++) {
            const int dim0 = a * 16 + qd * 4;           // 4 consecutive dims
            const int n0 = tileN + wn + dim0;
            const float4 bi = *(const float4*)&bias[n0];
#pragma unroll
            for (int b = 0; b < 4; b++) {
                const int m = tileM + wm + b * 16 + lm;
                const int t = m & (Tc - 1), bb = m >> 11;
                const float v0 = acc[a][b][0] + bi.x;
                const float v1 = acc[a][b][1] + bi.y;
                const float v2 = acc[a][b][2] + bi.z;
                const float v3 = acc[a][b][3] + bi.w;
                if (sec < 2) {
                    const float4 sn = *(const float4*)&sinT[t * 64 + dim0];
                    const float4 cs = *(const float4*)&cosT[t * 64 + dim0];
                    const float o0 = v0 * cs.x - v1 * sn.x;   // even dim
                    const float o1 = v1 * cs.y + v0 * sn.y;   // odd dim
                    const float o2 = v2 * cs.z - v3 * sn.z;
                    const float o3 = v3 * cs.w + v2 * sn.w;
                    union { __hip_bfloat16 hx[4]; ushort4 u4; } cv;
                    if (sec == 0) {
                        cv.hx[0] = (__hip_bfloat16)(o0 * QSCALE);
                        cv.hx[1] = (__hip_bfloat16)(o1 * QSCALE);
                        cv.hx[2] = (__hip_bfloat16)(o2 * QSCALE);
                        cv.hx[3] = (__hip_bfloat16)(o3 * QSCALE);
                        *(ushort4*)&Qb[((size_t)(bb * Hc + h) * Tc + t) * HDc + dim0] = cv.u4;
                    } else {
                        cv.hx[0] = (__hip_bfloat16)o0;
                        cv.hx[1] = (__hip_bfloat16)o1;
                        cv.hx[2] = (__hip_bfloat16)o2;
                        cv.hx[3] = (__hip_bfloat16)o3;
                        // K: XOR-swizzle (bits 3..5 only; 4 dims stay consecutive)
                        const int dswb = dim0 ^ ((t & 7) << 3);
                        *(ushort4*)&Kb[((size_t)(bb * Hc + h) * Tc + t) * HDc + dswb] = cv.u4;
                    }
                } else {
                    // V: f16, per-(b,h) transposed [dim][t], key order permuted+swizzled
                    const int u = t & 31;
                    const int posA = (t & ~31) + (((u & 15) >> 2) << 3)
                                     + ((u >> 4) << 2) + (u & 3);
                    const float vv[4] = {v0, v1, v2, v3};
#pragma unroll
                    for (int r = 0; r < 4; r++) {
                        const int dim = dim0 + r;
                        const int pos = posA ^ ((dim & 7) << 3);
                        Vb[((size_t)(bb * Hc + h) * HDc + dim) * Tc + pos] = (_Float16)vv[r];
                    }
                }
            }
        }
    } else {
#pragma unroll
        for (int a = 0; a < 4; a++) {
            const int n0 = tileN + wn + a * 16 + qd * 4;
            const float4 bi = *(const float4*)&bias[n0];
#pragma unroll
            for (int b = 0; b < 4; b++) {
                const int m = tileM + wm + b * 16 + lm;
                float4 o;
                o.x = acc[a][b][0] + bi.x;
                o.y = acc[a][b][1] + bi.y;
                o.z = acc[a][b][2] + bi.z;
                o.w = acc[a][b][3] + bi.w;
                *(float4*)&Cout[(size_t)m * N + n0] = o;
            }
        }
    }
}

// ---------------- flash attention, fixed-max softmax, S-ahead pipeline (T15) --------
// Bq=256/block (64 q/wave, qn=4). Bk=64 keys/tile, FOUR LDS buffers, staging
// depth 3 (stage kt+3 at top; counted vmcnt(4) per iter ensures tile kt+2 for
// the NEXT iteration's QK; never drains to 0 until tail — T4).
// Pipeline: iteration kt computes QK^T of tile kt+1 into registers, then
// exp2/cvt of tile kt+1 INTERLEAVED with rowsum+PV of tile kt (independent ->
// trans pipe overlaps matrix pipe instead of serializing QK->exp->PV).
// pf double-buffered via unroll-by-2 (pfA/pfB, all static indices).
// Buffer overwrite safety: stage((kt+3)&3) == buffer (kt-1)&3, whose sK was
// last read at iter kt-2 (QK of kt-1) and sV at iter kt-1 (PV) — >=1 barrier ago.
// Row-sums via ones-MFMA. S^T C-layout: the CONCAT of two 16-key S^T fragments
// == B-operand of mfma_f32_16x16x32_f16 under V's permuted key order (posA
// interleave) -> PV + rowsum run on the full-rate K=32 op.

__global__ __launch_bounds__(256, 2) void attn_kernel(
    const __hip_bfloat16* __restrict__ Qb, const __hip_bfloat16* __restrict__ Kb,
    const _Float16* __restrict__ Vh, __hip_bfloat16* __restrict__ AO)
{
    __shared__ __align__(16) __hip_bfloat16 sK[4][64 * 64];   // [key][dim^swz(key)]
    __shared__ __align__(16) _Float16 sV[4][64 * 64];         // [dim][perm-key^swz(dim)]
    const int tid = threadIdx.x, wave = tid >> 6, lane = tid & 63;
    const int qd = lane >> 4, lm = lane & 15;
    // XCD-aware mapping: block i -> XCD i%8; all 8 q-blocks of a bh on one XCD
    const int i = blockIdx.x;            // 512 blocks
    const int c = i & 7, j = i >> 3;     // j 0..63
    const int bh = c + 8 * (j >> 3);
    const int qblk = j & 7;
    const int q0 = qblk * 256 + wave * 64;

    const __hip_bfloat16* Qp = Qb + (size_t)bh * Tc * HDc;
    const __hip_bfloat16* Kp = Kb + (size_t)bh * Tc * HDc;
    const _Float16* Vp = Vh + (size_t)bh * HDc * Tc;

    bf16x8 qf[4][2];   // [qn][ks]: B-frag, lane: q=lm, k=ks*32+qd*8+j
#pragma unroll
    for (int qn = 0; qn < 4; qn++)
#pragma unroll
        for (int ks = 0; ks < 2; ks++)
            qf[qn][ks] = *(const bf16x8*)(Qp + (size_t)(q0 + qn * 16 + lm) * HDc
                                          + ks * 32 + qd * 8);

    f32x4 o[4][4];     // [qn][cb]: O^T, lane: q=lm, dim=cb*16+qd*4+r
    f32x4 lsum[4];     // [qn]: row-sum accumulator (all 4 regs identical)
#pragma unroll
    for (int qn = 0; qn < 4; qn++) {
#pragma unroll
        for (int cb = 0; cb < 4; cb++) o[qn][cb] = (f32x4){0.f, 0.f, 0.f, 0.f};
        lsum[qn] = (f32x4){0.f, 0.f, 0.f, 0.f};
    }
    const f16x8 one8 = {(_Float16)1.f, (_Float16)1.f, (_Float16)1.f, (_Float16)1.f,
                        (_Float16)1.f, (_Float16)1.f, (_Float16)1.f, (_Float16)1.f};

    const int swl = (lm & 7) << 3;

    // stage one 64-key tile (8 KB K + 8 KB V); 4 gld16 per wave
    auto stage = [&](int p, int k0) {
        const char* gK = (const char*)(Kp + (size_t)k0 * HDc);
#pragma unroll
        for (int jj = 0; jj < 2; jj++) {
            const int call = wave * 2 + jj;
            gld16(gK + call * 1024 + lane * 16,
                  (char*)&sK[p][0] + call * 1024 + lane * 16);
            const int dim = call * 8 + (lane >> 3);
            gld16((const char*)(Vp + (size_t)dim * Tc + k0 + (lane & 7) * 8),
                  (char*)&sV[p][0] + call * 1024 + lane * 16);
        }
    };

    // QK^T of one 64-key tile -> s[qn][nb] (nb = key-block 0..3)
    auto qk_into = [&](const __hip_bfloat16* bK, f32x4 (&s)[4][4]) {
#pragma unroll
        for (int nb = 0; nb < 4; nb++) {
            const int krow = nb * 16 + lm;
            bf16x8 kf0 = *(const bf16x8*)&bK[krow * 64 + ((0 + qd * 8) ^ swl)];
            bf16x8 kf1 = *(const bf16x8*)&bK[krow * 64 + ((32 + qd * 8) ^ swl)];
#pragma unroll
            for (int qn = 0; qn < 4; qn++) {
                f32x4 t = (f32x4){0.f, 0.f, 0.f, 0.f};
                t = __builtin_amdgcn_mfma_f32_16x16x32_bf16(kf0, qf[qn][0], t, 0, 0, 0);
                t = __builtin_amdgcn_mfma_f32_16x16x32_bf16(kf1, qf[qn][1], t, 0, 0, 0);
                s[qn][nb] = t;
            }
        }
    };

    // exp2 + pack of key-group g (key-blocks 2g, 2g+1) -> pf[qn][g]
    auto exp_into = [&](const f32x4 (&s)[4][4], int g, f16x8 (&pf)[4][2]) {
#pragma unroll
        for (int qn = 0; qn < 4; qn++) {
            const f32x4 a = s[qn][2 * g], b2 = s[qn][2 * g + 1];
            auto l0 = __builtin_amdgcn_cvt_pkrtz(EXP2F(a[0]), EXP2F(a[1]));
            auto l1 = __builtin_amdgcn_cvt_pkrtz(EXP2F(a[2]), EXP2F(a[3]));
            auto h0 = __builtin_amdgcn_cvt_pkrtz(EXP2F(b2[0]), EXP2F(b2[1]));
            auto h1 = __builtin_amdgcn_cvt_pkrtz(EXP2F(b2[2]), EXP2F(b2[3]));
            pf[qn][g][0] = l0[0]; pf[qn][g][1] = l0[1];
            pf[qn][g][2] = l1[0]; pf[qn][g][3] = l1[1];
            pf[qn][g][4] = h0[0]; pf[qn][g][5] = h0[1];
            pf[qn][g][6] = h1[0]; pf[qn][g][7] = h1[1];
        }
    };

    constexpr int NT = Tc / 64;          // 32 tiles
    stage(0, 0);
    stage(1, 64);
    stage(2, 128);
    __builtin_amdgcn_s_waitcnt(0xF74);   // vmcnt(4): tiles 0,1 landed (tile 2 in flight)
    __builtin_amdgcn_s_barrier();

    f16x8 pfA[4][2], pfB[4][2];
    {   // prologue: S(0) -> pfA
        f32x4 s0[4][4];
        qk_into(&sK[0][0], s0);
#pragma unroll
        for (int g = 0; g < 2; g++) exp_into(s0, g, pfA);
    }

    // one pipeline step: finish tile kt from pfC; prepare pfN for tile kt+1
    auto body = [&](int kt, f16x8 (&pfC)[4][2], f16x8 (&pfN)[4][2]) {
        const int p = kt & 3;
        if (kt + 3 < NT) stage((kt + 3) & 3, (kt + 3) * 64);

        f32x4 s[4][4];
        const bool hasN = (kt + 1 < NT);
        if (hasN) qk_into(&sK[(kt + 1) & 3][0], s);

        const _Float16* bV = &sV[p][0];
#pragma unroll
        for (int g = 0; g < 2; g++) {
            if (hasN) exp_into(s, g, pfN);     // trans pipe, independent of PV below
#pragma unroll
            for (int qn = 0; qn < 4; qn++)
                lsum[qn] = __builtin_amdgcn_mfma_f32_16x16x32_f16(
                    one8, pfC[qn][g], lsum[qn], 0, 0, 0);
#pragma unroll
            for (int cb = 0; cb < 4; cb++) {
                f16x8 v8 = *(const f16x8*)&bV[(cb * 16 + lm) * 64
                                              + ((g * 32 + qd * 8) ^ swl)];
#pragma unroll
                for (int qn = 0; qn < 4; qn++)
                    o[qn][cb] = __builtin_amdgcn_mfma_f32_16x16x32_f16(
                        v8, pfC[qn][g], o[qn][cb], 0, 0, 0);
            }
        }

        if (kt + 1 < NT) {
            if (kt + 3 < NT) __builtin_amdgcn_s_waitcnt(0xF74);  // vmcnt(4): tile kt+2 in
            else             __builtin_amdgcn_s_waitcnt(0xF70);  // vmcnt(0): drain tail
            __builtin_amdgcn_s_barrier();    // reads of overwritten buffers done
        }
    };

    for (int kt = 0; kt < NT; kt += 2) {
        body(kt, pfA, pfB);
        body(kt + 1, pfB, pfA);
    }

    const int b = bh >> 4, h = bh & 15;
#pragma unroll
    for (int qn = 0; qn < 4; qn++) {
        const float rinv = 1.f / lsum[qn][0];
        const int t = q0 + qn * 16 + lm;
#pragma unroll
        for (int cb = 0; cb < 4; cb++)
#pragma unroll
            for (int r = 0; r < 4; r++) {
                const int dim = cb * 16 + qd * 4 + r;
                AO[((size_t)b * Tc + t) * Dc + h * HDc + dim] =
                    (__hip_bfloat16)(o[qn][cb][r] * rinv);
            }
    }
}

// ---------------- launch ----------------

extern "C" void kernel_launch(void* const* d_in, const int* in_sizes, int n_in,
                              void* d_out, int out_size, void* d_ws, size_t ws_size,
                              hipStream_t stream)
{
    const float* x      = (const float*)d_in[0];
    const float* W_attn = (const float*)d_in[1];
    const float* b_attn = (const float*)d_in[2];
    const float* W_proj = (const float*)d_in[3];
    const float* b_proj = (const float*)d_in[4];
    float* out = (float*)d_out;

    char* w = (char*)d_ws;
    auto alloc = [&](size_t bytes) -> char* {
        char* p = w;
        w += (bytes + 255) & ~(size_t)255;
        return p;
    };
    __hip_bfloat16* xb  = (__hip_bfloat16*)alloc((size_t)Bc * Tc * Dc * 2);
    __hip_bfloat16* Wqt = (__hip_bfloat16*)alloc((size_t)3 * Dc * Dc * 2);
    __hip_bfloat16* Wpt = (__hip_bfloat16*)alloc((size_t)Dc * Dc * 2);
    __hip_bfloat16* Qb  = (__hip_bfloat16*)alloc((size_t)Bc * Hc * Tc * HDc * 2);
    __hip_bfloat16* Kb  = (__hip_bfloat16*)alloc((size_t)Bc * Hc * Tc * HDc * 2);
    _Float16*       Vh  = (_Float16*)alloc((size_t)Bc * Hc * Tc * HDc * 2);
    __hip_bfloat16* AO  = (__hip_bfloat16*)alloc((size_t)Bc * Tc * Dc * 2);
    float* sinT = (float*)alloc((size_t)Tc * 64 * 4);
    float* cosT = (float*)alloc((size_t)Tc * 64 * 4);

    const int M = Bc * Tc;  // 8192

    prep_kernel<<<dim3(3584), dim3(256), 0, stream>>>(
        (const float4*)x, (ushort4*)xb, W_attn, Wqt, W_proj, Wpt, sinT, cosT);

    gemm128<0><<<dim3(3 * Dc / 128, M / 128), dim3(256), 0, stream>>>(
        xb, Wqt, b_attn, M, 3 * Dc, Dc, sinT, cosT, Qb, Kb, Vh, nullptr);

    attn_kernel<<<dim3(512), dim3(256), 0, stream>>>(Qb, Kb, Vh, AO);

    gemm128<1><<<dim3(Dc / 128, M / 128), dim3(256), 0, stream>>>(
        AO, Wpt, b_proj, M, Dc, Dc, nullptr, nullptr, nullptr, nullptr, nullptr, out);
}

// Round 10
// 265.960 us; speedup vs baseline: 1.2730x; 1.2730x over previous
//
#include <hip/hip_runtime.h>
#include <hip/hip_bf16.h>
#include <stdint.h>

#define DEVI __device__ __forceinline__

using bf16x8 = __attribute__((ext_vector_type(8))) short;
using f32x4  = __attribute__((ext_vector_type(4))) float;
using f16x4  = __attribute__((ext_vector_type(4))) _Float16;
using f16x8  = __attribute__((ext_vector_type(8))) _Float16;

static constexpr int Bc = 4;
static constexpr int Tc = 2048;
static constexpr int Dc = 1024;
static constexpr int Hc = 16;
static constexpr int HDc = 64;
// 1/sqrt(512) * log2(e), folded into Q so softmax uses exp2 directly
#define QSCALE 0.06375788883274286f

#if __has_builtin(__builtin_amdgcn_exp2f)
#define EXP2F __builtin_amdgcn_exp2f
#else
#define EXP2F exp2f
#endif

typedef const unsigned int __attribute__((address_space(1)))* gas1_t;
typedef unsigned int __attribute__((address_space(3)))* las3_t;

DEVI void gld16(const void* g, void* l)
{
    __builtin_amdgcn_global_load_lds((gas1_t)(uintptr_t)g, (las3_t)(uintptr_t)l, 16, 0, 0);
}

// ---------------- fused prep kernel ----------------
// One launch, block-range partitioned (saves 3 kernel launch gaps):
//   blocks [0,2048):     x fp32 -> bf16 (64B/thread, block-strided)
//   blocks [2048,2816):  W_attn [K][N] fp32 -> Wqt [N][K] bf16 (64x64 tiles)
//   blocks [2816,3072):  W_proj -> Wpt
//   blocks [3072,3584):  RoPE sin/cos tables

DEVI void transpose_tile(const float* __restrict__ W, __hip_bfloat16* __restrict__ Wt,
                         int K, int N, int n0, int k0, float (*tile)[65], int tid)
{
    const int tx = tid & 15, ty = tid >> 4;   // 16 x 16
#pragma unroll
    for (int i2 = 0; i2 < 4; i2++) {
        const int k = ty + 16 * i2;
        float4 v = *(const float4*)&W[(size_t)(k0 + k) * N + n0 + tx * 4];
        tile[tx * 4 + 0][k] = v.x;
        tile[tx * 4 + 1][k] = v.y;
        tile[tx * 4 + 2][k] = v.z;
        tile[tx * 4 + 3][k] = v.w;
    }
    __syncthreads();
#pragma unroll
    for (int i2 = 0; i2 < 4; i2++) {
        const int n = ty + 16 * i2;
        union { __hip_bfloat16 h[4]; ushort4 u4; } cv;
#pragma unroll
        for (int c = 0; c < 4; c++)
            cv.h[c] = (__hip_bfloat16)tile[n][tx * 4 + c];
        *(ushort4*)&Wt[(size_t)(n0 + n) * K + k0 + tx * 4] = cv.u4;
    }
}

__global__ __launch_bounds__(256) void prep_kernel(
    const float4* __restrict__ x, ushort4* __restrict__ xb,
    const float* __restrict__ W_attn, __hip_bfloat16* __restrict__ Wqt,
    const float* __restrict__ W_proj, __hip_bfloat16* __restrict__ Wpt,
    float* __restrict__ sinT, float* __restrict__ cosT)
{
    __shared__ float tile[64][65];
    const int bid = blockIdx.x, tid = threadIdx.x;
    if (bid < 2048) {
        const int base = bid * 1024 + tid;
#pragma unroll
        for (int u = 0; u < 4; u++) {
            const int i = base + u * 256;
            float4 v = x[i];
            union { __hip_bfloat16 h[4]; ushort4 u4; } cv;
            cv.h[0] = __float2bfloat16(v.x);
            cv.h[1] = __float2bfloat16(v.y);
            cv.h[2] = __float2bfloat16(v.z);
            cv.h[3] = __float2bfloat16(v.w);
            xb[i] = cv.u4;
        }
    } else if (bid < 2816) {
        const int b2 = bid - 2048;                    // grid was (48, 16)
        transpose_tile(W_attn, Wqt, Dc, 3 * Dc, (b2 % 48) * 64, (b2 / 48) * 64, tile, tid);
    } else if (bid < 3072) {
        const int b3 = bid - 2816;                    // grid was (16, 16)
        transpose_tile(W_proj, Wpt, Dc, Dc, (b3 % 16) * 64, (b3 / 16) * 64, tile, tid);
    } else {
        const int i = (bid - 3072) * 256 + tid;       // Tc*64 total
        const int t = i >> 6, dim = i & 63;
        const int p = dim >> 1;
        float theta = powf(1000.f, -2.f * (float)(p + 1) / 64.f);
        float arg = (float)(t + 1) * theta;
        sinT[i] = sinf(arg);
        cosT[i] = cosf(arg);
    }
}

// ---------------- GEMM: 128x128 tile, TRANSPOSED C-orientation ----------------
// A-operand = weight rows (n), B-operand = x rows (m) -> D[n][m].
// K-loop: m97 structure — SINGLE-buffered LDS (32 KB -> ~4 blocks/CU), plain
// drain loop {stage -> vmcnt(0) -> barrier -> compute -> barrier}. Pipelining
// comes from implicit wave-level overlap across co-resident blocks (m114).
// (Round-8 A/B: this beats the 64 KB explicit dbuf 77.8 vs 79 us. Round-9:
// register S-ahead pipelining in attn SPILLED to scratch — do not re-attempt
// deep register pipelines on these structures.)
// LDS octet XOR-swizzle (pre-swizzled GLOBAL source + swizzled read; LDS linear,
// rule #21) kills the 16-way ds_read_b128 bank conflict.
// MODE 0: QKV epilogue (RoPE; Q scaled; K dim-swizzled; V -> f16 transposed+permuted)
// MODE 1: proj epilogue (fp32 out + bias)

template <int MODE>
__global__ __launch_bounds__(256, 4) void gemm128(
    const __hip_bfloat16* __restrict__ A, const __hip_bfloat16* __restrict__ Bt,
    const float* __restrict__ bias, int M, int N, int K,
    const float* __restrict__ sinT, const float* __restrict__ cosT,
    __hip_bfloat16* __restrict__ Qb, __hip_bfloat16* __restrict__ Kb,
    _Float16* __restrict__ Vb, float* __restrict__ Cout)
{
    __shared__ __align__(16) __hip_bfloat16 sA[128 * 64];
    __shared__ __align__(16) __hip_bfloat16 sB[128 * 64];
    const int tid = threadIdx.x;
    const int wave = tid >> 6, lane = tid & 63;
    const int qd = lane >> 4, lm = lane & 15;
    const int wm = (wave >> 1) * 64, wn = (wave & 1) * 64;
    const int tileM = blockIdx.y * 128, tileN = blockIdx.x * 128;

    const int srow = tid >> 3;                      // 0..31 (staged row within chunk)
    const int socc = (tid & 7) ^ (srow & 7);        // swizzled source octet

    f32x4 acc[4][4];                    // [a: n-block][b: m-block]
#pragma unroll
    for (int i = 0; i < 4; i++)
#pragma unroll
        for (int j = 0; j < 4; j++)
            acc[i][j] = (f32x4){0.f, 0.f, 0.f, 0.f};

    // LDS[row][o] holds global octet o ^ (row&7); rows stay linear for gld16
    const __hip_bfloat16* pa = A + (size_t)(tileM + srow) * K + socc * 8;
    const __hip_bfloat16* pb = Bt + (size_t)(tileN + srow) * K + socc * 8;

    auto stageT = [&](int k0) {
#pragma unroll
        for (int it = 0; it < 4; it++) {
            gld16(pa + (size_t)(it * 32) * K + k0, &sA[it * 2048 + wave * 512]);
            gld16(pb + (size_t)(it * 32) * K + k0, &sB[it * 2048 + wave * 512]);
        }
    };

    const int swl = (lm & 7) << 3;      // read-side octet swizzle (row&7 == lm&7)
    const int nk = K / 64;
    for (int kt = 0; kt < nk; kt++) {
        stageT(kt * 64);
        __builtin_amdgcn_s_waitcnt(0xF70);       // vmcnt(0): tile kt landed
        __builtin_amdgcn_s_barrier();            // all waves' loads landed

#pragma unroll
        for (int ks = 0; ks < 2; ks++) {
            bf16x8 wf[4], xf[4];
#pragma unroll
            for (int a = 0; a < 4; a++)
                wf[a] = *(const bf16x8*)&sB[(wn + a * 16 + lm) * 64
                                            + ((ks * 32 + qd * 8) ^ swl)];
#pragma unroll
            for (int b = 0; b < 4; b++)
                xf[b] = *(const bf16x8*)&sA[(wm + b * 16 + lm) * 64
                                            + ((ks * 32 + qd * 8) ^ swl)];
#pragma unroll
            for (int a = 0; a < 4; a++)
#pragma unroll
                for (int b = 0; b < 4; b++)
                    acc[a][b] = __builtin_amdgcn_mfma_f32_16x16x32_bf16(
                        wf[a], xf[b], acc[a][b], 0, 0, 0);
        }
        if (kt + 1 < nk)
            __builtin_amdgcn_s_barrier();        // reads done before next overwrite
    }

    if constexpr (MODE == 0) {
        const int sec = tileN >> 10;                    // q/k/v section, block-uniform
        const int h = ((tileN + wn) & 1023) >> 6;       // head, wave-uniform
#pragma unroll
        for (int a = 0; a < 4; a++) {
            const int dim0 = a * 16 + qd * 4;           // 4 consecutive dims
            const int n0 = tileN + wn + dim0;
            const float4 bi = *(const float4*)&bias[n0];
#pragma unroll
            for (int b = 0; b < 4; b++) {
                const int m = tileM + wm + b * 16 + lm;
                const int t = m & (Tc - 1), bb = m >> 11;
                const float v0 = acc[a][b][0] + bi.x;
                const float v1 = acc[a][b][1] + bi.y;
                const float v2 = acc[a][b][2] + bi.z;
                const float v3 = acc[a][b][3] + bi.w;
                if (sec < 2) {
                    const float4 sn = *(const float4*)&sinT[t * 64 + dim0];
                    const float4 cs = *(const float4*)&cosT[t * 64 + dim0];
                    const float o0 = v0 * cs.x - v1 * sn.x;   // even dim
                    const float o1 = v1 * cs.y + v0 * sn.y;   // odd dim
                    const float o2 = v2 * cs.z - v3 * sn.z;
                    const float o3 = v3 * cs.w + v2 * sn.w;
                    union { __hip_bfloat16 hx[4]; ushort4 u4; } cv;
                    if (sec == 0) {
                        cv.hx[0] = (__hip_bfloat16)(o0 * QSCALE);
                        cv.hx[1] = (__hip_bfloat16)(o1 * QSCALE);
                        cv.hx[2] = (__hip_bfloat16)(o2 * QSCALE);
                        cv.hx[3] = (__hip_bfloat16)(o3 * QSCALE);
                        *(ushort4*)&Qb[((size_t)(bb * Hc + h) * Tc + t) * HDc + dim0] = cv.u4;
                    } else {
                        cv.hx[0] = (__hip_bfloat16)o0;
                        cv.hx[1] = (__hip_bfloat16)o1;
                        cv.hx[2] = (__hip_bfloat16)o2;
                        cv.hx[3] = (__hip_bfloat16)o3;
                        // K: XOR-swizzle (bits 3..5 only; 4 dims stay consecutive)
                        const int dswb = dim0 ^ ((t & 7) << 3);
                        *(ushort4*)&Kb[((size_t)(bb * Hc + h) * Tc + t) * HDc + dswb] = cv.u4;
                    }
                } else {
                    // V: f16, per-(b,h) transposed [dim][t], key order permuted+swizzled
                    const int u = t & 31;
                    const int posA = (t & ~31) + (((u & 15) >> 2) << 3)
                                     + ((u >> 4) << 2) + (u & 3);
                    const float vv[4] = {v0, v1, v2, v3};
#pragma unroll
                    for (int r = 0; r < 4; r++) {
                        const int dim = dim0 + r;
                        const int pos = posA ^ ((dim & 7) << 3);
                        Vb[((size_t)(bb * Hc + h) * HDc + dim) * Tc + pos] = (_Float16)vv[r];
                    }
                }
            }
        }
    } else {
#pragma unroll
        for (int a = 0; a < 4; a++) {
            const int n0 = tileN + wn + a * 16 + qd * 4;
            const float4 bi = *(const float4*)&bias[n0];
#pragma unroll
            for (int b = 0; b < 4; b++) {
                const int m = tileM + wm + b * 16 + lm;
                float4 o;
                o.x = acc[a][b][0] + bi.x;
                o.y = acc[a][b][1] + bi.y;
                o.z = acc[a][b][2] + bi.z;
                o.w = acc[a][b][3] + bi.w;
                *(float4*)&Cout[(size_t)m * N + n0] = o;
            }
        }
    }
}

// ---------------- flash attention, fixed-max softmax, depth-2 pipelined KV ----------------
// Bq=256/block (64 q/wave, qn=4). Bk=64 keys/tile, FOUR LDS buffers (64 KB).
// Per iter: stage tile kt+2, compute tile kt, counted vmcnt(4) (waits only tile
// kt+1's 4 loads; never drains to 0 until tail — T4), ONE s_barrier.
// Buffer reused 4 tiles later -> 2-barrier safety margin. Occupancy is
// GRID-limited (512 blocks = 2/CU), so LDS 64 KB costs nothing here.
// Row-sums via ones-MFMA. S^T C-layout: the CONCAT of two 16-key S^T fragments
// == B-operand of mfma_f32_16x16x32_f16 under V's permuted key order (posA
// interleave) -> PV + rowsum run on the full-rate K=32 op.
// (Round-9: register S-ahead pipeline spilled -> 147 us. Keep this form.)

__global__ __launch_bounds__(256, 2) void attn_kernel(
    const __hip_bfloat16* __restrict__ Qb, const __hip_bfloat16* __restrict__ Kb,
    const _Float16* __restrict__ Vh, __hip_bfloat16* __restrict__ AO)
{
    __shared__ __align__(16) __hip_bfloat16 sK[4][64 * 64];   // [key][dim^swz(key)]
    __shared__ __align__(16) _Float16 sV[4][64 * 64];         // [dim][perm-key^swz(dim)]
    const int tid = threadIdx.x, wave = tid >> 6, lane = tid & 63;
    const int qd = lane >> 4, lm = lane & 15;
    // XCD-aware mapping: block i -> XCD i%8; all 8 q-blocks of a bh on one XCD
    const int i = blockIdx.x;            // 512 blocks
    const int c = i & 7, j = i >> 3;     // j 0..63
    const int bh = c + 8 * (j >> 3);
    const int qblk = j & 7;
    const int q0 = qblk * 256 + wave * 64;

    const __hip_bfloat16* Qp = Qb + (size_t)bh * Tc * HDc;
    const __hip_bfloat16* Kp = Kb + (size_t)bh * Tc * HDc;
    const _Float16* Vp = Vh + (size_t)bh * HDc * Tc;

    bf16x8 qf[4][2];   // [qn][ks]: B-frag, lane: q=lm, k=ks*32+qd*8+j
#pragma unroll
    for (int qn = 0; qn < 4; qn++)
#pragma unroll
        for (int ks = 0; ks < 2; ks++)
            qf[qn][ks] = *(const bf16x8*)(Qp + (size_t)(q0 + qn * 16 + lm) * HDc
                                          + ks * 32 + qd * 8);

    f32x4 o[4][4];     // [qn][cb]: O^T, lane: q=lm, dim=cb*16+qd*4+r
    f32x4 lsum[4];     // [qn]: row-sum accumulator (all 4 regs identical)
#pragma unroll
    for (int qn = 0; qn < 4; qn++) {
#pragma unroll
        for (int cb = 0; cb < 4; cb++) o[qn][cb] = (f32x4){0.f, 0.f, 0.f, 0.f};
        lsum[qn] = (f32x4){0.f, 0.f, 0.f, 0.f};
    }
    const f16x8 one8 = {(_Float16)1.f, (_Float16)1.f, (_Float16)1.f, (_Float16)1.f,
                        (_Float16)1.f, (_Float16)1.f, (_Float16)1.f, (_Float16)1.f};

    const int swl = (lm & 7) << 3;

    // stage one 64-key tile (8 KB K + 8 KB V); 4 gld16 per wave
    auto stage = [&](int p, int k0) {
        const char* gK = (const char*)(Kp + (size_t)k0 * HDc);
#pragma unroll
        for (int jj = 0; jj < 2; jj++) {
            const int call = wave * 2 + jj;
            gld16(gK + call * 1024 + lane * 16,
                  (char*)&sK[p][0] + call * 1024 + lane * 16);
            const int dim = call * 8 + (lane >> 3);
            gld16((const char*)(Vp + (size_t)dim * Tc + k0 + (lane & 7) * 8),
                  (char*)&sV[p][0] + call * 1024 + lane * 16);
        }
    };

    constexpr int NT = Tc / 64;          // 32 tiles
    stage(0, 0);
    stage(1, 64);
    __builtin_amdgcn_s_waitcnt(0xF74);   // vmcnt(4): tile 0 landed (tile 1 in flight)
    __builtin_amdgcn_s_barrier();

    for (int kt = 0; kt < NT; kt++) {
        const int p = kt & 3;
        if (kt + 2 < NT) stage((kt + 2) & 3, (kt + 2) * 64);

        const __hip_bfloat16* bK = &sK[p][0];
        const _Float16* bV = &sV[p][0];

        // ---- S^T = K @ Q^T over 64 keys; P = exp2(S) straight away ----
        // pf8[qn][g] = concat of key-blocks 2g (elems 0-3) and 2g+1 (elems 4-7):
        // lane (qd,lm) holds keys {32g+4qd+0..3, 32g+16+4qd+0..3} — exactly V's
        // stored key order at positions 32g+8qd+{0..7}.
        f16x8 pf8[4][2];
#pragma unroll
        for (int g = 0; g < 2; g++) {
#pragma unroll
            for (int hh = 0; hh < 2; hh++) {
                const int krow = (2 * g + hh) * 16 + lm;
                bf16x8 kf0 = *(const bf16x8*)&bK[krow * 64 + ((0 + qd * 8) ^ swl)];
                bf16x8 kf1 = *(const bf16x8*)&bK[krow * 64 + ((32 + qd * 8) ^ swl)];
#pragma unroll
                for (int qn = 0; qn < 4; qn++) {
                    f32x4 s = (f32x4){0.f, 0.f, 0.f, 0.f};
                    s = __builtin_amdgcn_mfma_f32_16x16x32_bf16(kf0, qf[qn][0], s, 0, 0, 0);
                    s = __builtin_amdgcn_mfma_f32_16x16x32_bf16(kf1, qf[qn][1], s, 0, 0, 0);
                    auto lo = __builtin_amdgcn_cvt_pkrtz(EXP2F(s[0]), EXP2F(s[1]));
                    auto hi = __builtin_amdgcn_cvt_pkrtz(EXP2F(s[2]), EXP2F(s[3]));
                    pf8[qn][g][4 * hh + 0] = lo[0];
                    pf8[qn][g][4 * hh + 1] = lo[1];
                    pf8[qn][g][4 * hh + 2] = hi[0];
                    pf8[qn][g][4 * hh + 3] = hi[1];
                }
            }
        }

        // ---- row sums on the matrix pipe: lsum += 1 * P^T (K=32) ----
#pragma unroll
        for (int qn = 0; qn < 4; qn++)
#pragma unroll
            for (int g = 0; g < 2; g++)
                lsum[qn] = __builtin_amdgcn_mfma_f32_16x16x32_f16(
                    one8, pf8[qn][g], lsum[qn], 0, 0, 0);

        // ---- O^T += V^T @ P^T, register-direct, full-rate K=32 f16 MFMA ----
#pragma unroll
        for (int g = 0; g < 2; g++) {
#pragma unroll
            for (int cb = 0; cb < 4; cb++) {
                f16x8 v8 = *(const f16x8*)&bV[(cb * 16 + lm) * 64
                                              + ((g * 32 + qd * 8) ^ swl)];
#pragma unroll
                for (int qn = 0; qn < 4; qn++)
                    o[qn][cb] = __builtin_amdgcn_mfma_f32_16x16x32_f16(
                        v8, pf8[qn][g], o[qn][cb], 0, 0, 0);
            }
        }

        if (kt + 1 < NT) {
            if (kt + 2 < NT) __builtin_amdgcn_s_waitcnt(0xF74);  // vmcnt(4): tile kt+1 in
            else             __builtin_amdgcn_s_waitcnt(0xF70);  // vmcnt(0): drain tail
            __builtin_amdgcn_s_barrier();    // reads of p done + tile kt+1 visible
        }
    }

    const int b = bh >> 4, h = bh & 15;
#pragma unroll
    for (int qn = 0; qn < 4; qn++) {
        const float rinv = 1.f / lsum[qn][0];
        const int t = q0 + qn * 16 + lm;
#pragma unroll
        for (int cb = 0; cb < 4; cb++)
#pragma unroll
            for (int r = 0; r < 4; r++) {
                const int dim = cb * 16 + qd * 4 + r;
                AO[((size_t)b * Tc + t) * Dc + h * HDc + dim] =
                    (__hip_bfloat16)(o[qn][cb][r] * rinv);
            }
    }
}

// ---------------- launch ----------------

extern "C" void kernel_launch(void* const* d_in, const int* in_sizes, int n_in,
                              void* d_out, int out_size, void* d_ws, size_t ws_size,
                              hipStream_t stream)
{
    const float* x      = (const float*)d_in[0];
    const float* W_attn = (const float*)d_in[1];
    const float* b_attn = (const float*)d_in[2];
    const float* W_proj = (const float*)d_in[3];
    const float* b_proj = (const float*)d_in[4];
    float* out = (float*)d_out;

    char* w = (char*)d_ws;
    auto alloc = [&](size_t bytes) -> char* {
        char* p = w;
        w += (bytes + 255) & ~(size_t)255;
        return p;
    };
    __hip_bfloat16* xb  = (__hip_bfloat16*)alloc((size_t)Bc * Tc * Dc * 2);
    __hip_bfloat16* Wqt = (__hip_bfloat16*)alloc((size_t)3 * Dc * Dc * 2);
    __hip_bfloat16* Wpt = (__hip_bfloat16*)alloc((size_t)Dc * Dc * 2);
    __hip_bfloat16* Qb  = (__hip_bfloat16*)alloc((size_t)Bc * Hc * Tc * HDc * 2);
    __hip_bfloat16* Kb  = (__hip_bfloat16*)alloc((size_t)Bc * Hc * Tc * HDc * 2);
    _Float16*       Vh  = (_Float16*)alloc((size_t)Bc * Hc * Tc * HDc * 2);
    __hip_bfloat16* AO  = (__hip_bfloat16*)alloc((size_t)Bc * Tc * Dc * 2);
    float* sinT = (float*)alloc((size_t)Tc * 64 * 4);
    float* cosT = (float*)alloc((size_t)Tc * 64 * 4);

    const int M = Bc * Tc;  // 8192

    prep_kernel<<<dim3(3584), dim3(256), 0, stream>>>(
        (const float4*)x, (ushort4*)xb, W_attn, Wqt, W_proj, Wpt, sinT, cosT);

    gemm128<0><<<dim3(3 * Dc / 128, M / 128), dim3(256), 0, stream>>>(
        xb, Wqt, b_attn, M, 3 * Dc, Dc, sinT, cosT, Qb, Kb, Vh, nullptr);

    attn_kernel<<<dim3(512), dim3(256), 0, stream>>>(Qb, Kb, Vh, AO);

    gemm128<1><<<dim3(Dc / 128, M / 128), dim3(256), 0, stream>>>(
        AO, Wpt, b_proj, M, Dc, Dc, nullptr, nullptr, nullptr, nullptr, nullptr, out);
}

// Round 11
// 262.258 us; speedup vs baseline: 1.2910x; 1.0141x over previous
//
#include <hip/hip_runtime.h>
#include <hip/hip_bf16.h>
#include <stdint.h>

#define DEVI __device__ __forceinline__

using bf16x8 = __attribute__((ext_vector_type(8))) short;
using f32x4  = __attribute__((ext_vector_type(4))) float;
using f16x4  = __attribute__((ext_vector_type(4))) _Float16;
using f16x8  = __attribute__((ext_vector_type(8))) _Float16;

static constexpr int Bc = 4;
static constexpr int Tc = 2048;
static constexpr int Dc = 1024;
static constexpr int Hc = 16;
static constexpr int HDc = 64;
// 1/sqrt(512) * log2(e), folded into Q so softmax uses exp2 directly
#define QSCALE 0.06375788883274286f

#if __has_builtin(__builtin_amdgcn_exp2f)
#define EXP2F __builtin_amdgcn_exp2f
#else
#define EXP2F exp2f
#endif

typedef const unsigned int __attribute__((address_space(1)))* gas1_t;
typedef unsigned int __attribute__((address_space(3)))* las3_t;

DEVI void gld16(const void* g, void* l)
{
    __builtin_amdgcn_global_load_lds((gas1_t)(uintptr_t)g, (las3_t)(uintptr_t)l, 16, 0, 0);
}

// ---------------- fused prep kernel ----------------
// One launch, block-range partitioned (saves 3 kernel launch gaps):
//   blocks [0,2048):     x fp32 -> bf16 (64B/thread, block-strided)
//   blocks [2048,2816):  W_attn [K][N] fp32 -> Wqt [N][K] bf16 (64x64 tiles)
//   blocks [2816,3072):  W_proj -> Wpt
//   blocks [3072,3584):  RoPE sin/cos tables

DEVI void transpose_tile(const float* __restrict__ W, __hip_bfloat16* __restrict__ Wt,
                         int K, int N, int n0, int k0, float (*tile)[65], int tid)
{
    const int tx = tid & 15, ty = tid >> 4;   // 16 x 16
#pragma unroll
    for (int i2 = 0; i2 < 4; i2++) {
        const int k = ty + 16 * i2;
        float4 v = *(const float4*)&W[(size_t)(k0 + k) * N + n0 + tx * 4];
        tile[tx * 4 + 0][k] = v.x;
        tile[tx * 4 + 1][k] = v.y;
        tile[tx * 4 + 2][k] = v.z;
        tile[tx * 4 + 3][k] = v.w;
    }
    __syncthreads();
#pragma unroll
    for (int i2 = 0; i2 < 4; i2++) {
        const int n = ty + 16 * i2;
        union { __hip_bfloat16 h[4]; ushort4 u4; } cv;
#pragma unroll
        for (int c = 0; c < 4; c++)
            cv.h[c] = (__hip_bfloat16)tile[n][tx * 4 + c];
        *(ushort4*)&Wt[(size_t)(n0 + n) * K + k0 + tx * 4] = cv.u4;
    }
}

__global__ __launch_bounds__(256) void prep_kernel(
    const float4* __restrict__ x, ushort4* __restrict__ xb,
    const float* __restrict__ W_attn, __hip_bfloat16* __restrict__ Wqt,
    const float* __restrict__ W_proj, __hip_bfloat16* __restrict__ Wpt,
    float* __restrict__ sinT, float* __restrict__ cosT)
{
    __shared__ float tile[64][65];
    const int bid = blockIdx.x, tid = threadIdx.x;
    if (bid < 2048) {
        const int base = bid * 1024 + tid;
#pragma unroll
        for (int u = 0; u < 4; u++) {
            const int i = base + u * 256;
            float4 v = x[i];
            union { __hip_bfloat16 h[4]; ushort4 u4; } cv;
            cv.h[0] = __float2bfloat16(v.x);
            cv.h[1] = __float2bfloat16(v.y);
            cv.h[2] = __float2bfloat16(v.z);
            cv.h[3] = __float2bfloat16(v.w);
            xb[i] = cv.u4;
        }
    } else if (bid < 2816) {
        const int b2 = bid - 2048;                    // grid was (48, 16)
        transpose_tile(W_attn, Wqt, Dc, 3 * Dc, (b2 % 48) * 64, (b2 / 48) * 64, tile, tid);
    } else if (bid < 3072) {
        const int b3 = bid - 2816;                    // grid was (16, 16)
        transpose_tile(W_proj, Wpt, Dc, Dc, (b3 % 16) * 64, (b3 / 16) * 64, tile, tid);
    } else {
        const int i = (bid - 3072) * 256 + tid;       // Tc*64 total
        const int t = i >> 6, dim = i & 63;
        const int p = dim >> 1;
        float theta = powf(1000.f, -2.f * (float)(p + 1) / 64.f);
        float arg = (float)(t + 1) * theta;
        sinT[i] = sinf(arg);
        cosT[i] = cosf(arg);
    }
}

// ---------------- GEMM: 128x128 tile, TRANSPOSED C-orientation ----------------
// A-operand = weight rows (n), B-operand = x rows (m) -> D[n][m].
// K-loop: m97 structure — SINGLE-buffered LDS (32 KB -> ~4 blocks/CU), plain
// drain loop {stage -> vmcnt(0) -> barrier -> compute -> barrier}. Pipelining
// from implicit wave-level overlap across co-resident blocks (m114).
// LDS octet XOR-swizzle (pre-swizzled GLOBAL source + swizzled read; LDS linear,
// rule #21) kills the 16-way ds_read_b128 bank conflict.
// MODE 0 epilogue (NEW, round 11): outputs bounced through the freed 32 KB LDS
// (128x128x2B exact fit), then stored COALESCED — each wave store-instr covers
// 8 full 128B rows (was: Q/K 16 lines/instr @8B, V 2B scalar scatter). K's
// per-t dim-XOR and V's pos-permutation are octet-granular -> folded into the
// readback octet index with coalescing intact. Values bit-identical.
// MODE 1: proj epilogue (fp32 out + bias), unchanged.

template <int MODE>
__global__ __launch_bounds__(256, 4) void gemm128(
    const __hip_bfloat16* __restrict__ A, const __hip_bfloat16* __restrict__ Bt,
    const float* __restrict__ bias, int M, int N, int K,
    const float* __restrict__ sinT, const float* __restrict__ cosT,
    __hip_bfloat16* __restrict__ Qb, __hip_bfloat16* __restrict__ Kb,
    _Float16* __restrict__ Vb, float* __restrict__ Cout)
{
    __shared__ __align__(16) __hip_bfloat16 smem[2][128 * 64];
    __hip_bfloat16* sA = smem[0];
    __hip_bfloat16* sB = smem[1];
    const int tid = threadIdx.x;
    const int wave = tid >> 6, lane = tid & 63;
    const int qd = lane >> 4, lm = lane & 15;
    const int wm = (wave >> 1) * 64, wn = (wave & 1) * 64;
    const int tileM = blockIdx.y * 128, tileN = blockIdx.x * 128;

    const int srow = tid >> 3;                      // 0..31 (staged row within chunk)
    const int socc = (tid & 7) ^ (srow & 7);        // swizzled source octet

    f32x4 acc[4][4];                    // [a: n-block][b: m-block]
#pragma unroll
    for (int i = 0; i < 4; i++)
#pragma unroll
        for (int j = 0; j < 4; j++)
            acc[i][j] = (f32x4){0.f, 0.f, 0.f, 0.f};

    // LDS[row][o] holds global octet o ^ (row&7); rows stay linear for gld16
    const __hip_bfloat16* pa = A + (size_t)(tileM + srow) * K + socc * 8;
    const __hip_bfloat16* pb = Bt + (size_t)(tileN + srow) * K + socc * 8;

    auto stageT = [&](int k0) {
#pragma unroll
        for (int it = 0; it < 4; it++) {
            gld16(pa + (size_t)(it * 32) * K + k0, &sA[it * 2048 + wave * 512]);
            gld16(pb + (size_t)(it * 32) * K + k0, &sB[it * 2048 + wave * 512]);
        }
    };

    const int swl = (lm & 7) << 3;      // read-side octet swizzle (row&7 == lm&7)
    const int nk = K / 64;
    for (int kt = 0; kt < nk; kt++) {
        stageT(kt * 64);
        __builtin_amdgcn_s_waitcnt(0xF70);       // vmcnt(0): tile kt landed
        __builtin_amdgcn_s_barrier();            // all waves' loads landed

#pragma unroll
        for (int ks = 0; ks < 2; ks++) {
            bf16x8 wf[4], xf[4];
#pragma unroll
            for (int a = 0; a < 4; a++)
                wf[a] = *(const bf16x8*)&sB[(wn + a * 16 + lm) * 64
                                            + ((ks * 32 + qd * 8) ^ swl)];
#pragma unroll
            for (int b = 0; b < 4; b++)
                xf[b] = *(const bf16x8*)&sA[(wm + b * 16 + lm) * 64
                                            + ((ks * 32 + qd * 8) ^ swl)];
#pragma unroll
            for (int a = 0; a < 4; a++)
#pragma unroll
                for (int b = 0; b < 4; b++)
                    acc[a][b] = __builtin_amdgcn_mfma_f32_16x16x32_bf16(
                        wf[a], xf[b], acc[a][b], 0, 0, 0);
        }
        if (kt + 1 < nk)
            __builtin_amdgcn_s_barrier();        // reads done before next overwrite
    }

    if constexpr (MODE == 0) {
        __syncthreads();                          // K-loop LDS now reusable
        __hip_bfloat16* ep = &smem[0][0];         // 128x128 bounce tile (32 KB)
        const int sec = tileN >> 10;              // q/k/v section, block-uniform
        const int hb = (tileN & 1023) >> 6;       // first head of this tile
        const int bbu = tileM >> 11;              // batch, block-uniform
        const int tb = tileM & (Tc - 1);          // t-base, 128-aligned

        if (sec < 2) {
            // ---- write side: RoPE in-reg, pack 4 dims, swizzled b64 LDS write ----
#pragma unroll
            for (int a = 0; a < 4; a++) {
                const int n0l = wn + a * 16 + qd * 4;   // local n, 0..127
                const int dim0 = n0l & 63;              // dim within head
                const float4 bi = *(const float4*)&bias[tileN + n0l];
#pragma unroll
                for (int b = 0; b < 4; b++) {
                    const int ml = wm + b * 16 + lm;    // local m, 0..127
                    const int t = tb + ml;
                    const float v0 = acc[a][b][0] + bi.x;
                    const float v1 = acc[a][b][1] + bi.y;
                    const float v2 = acc[a][b][2] + bi.z;
                    const float v3 = acc[a][b][3] + bi.w;
                    const float4 sn = *(const float4*)&sinT[t * 64 + dim0];
                    const float4 cs = *(const float4*)&cosT[t * 64 + dim0];
                    float o0 = v0 * cs.x - v1 * sn.x;   // even dim
                    float o1 = v1 * cs.y + v0 * sn.y;   // odd dim
                    float o2 = v2 * cs.z - v3 * sn.z;
                    float o3 = v3 * cs.w + v2 * sn.w;
                    if (sec == 0) {
                        o0 *= QSCALE; o1 *= QSCALE; o2 *= QSCALE; o3 *= QSCALE;
                    }
                    union { __hip_bfloat16 hx[4]; ushort4 u4; } cv;
                    cv.hx[0] = (__hip_bfloat16)o0;
                    cv.hx[1] = (__hip_bfloat16)o1;
                    cv.hx[2] = (__hip_bfloat16)o2;
                    cv.hx[3] = (__hip_bfloat16)o3;
                    // bank-swizzle: XOR octet index by ml&7 (4-el granule safe)
                    *(ushort4*)&ep[ml * 128 + (n0l ^ ((ml & 7) << 3))] = cv.u4;
                }
            }
            __syncthreads();
            // ---- readback + coalesced store: lanes 0-7 = one t-row's octets ----
#pragma unroll
            for (int r = 0; r < 8; r++) {
                const int tl = (tid >> 3) + 32 * (r & 3);   // t-row 0..127
                const int oo = (tid & 7) + 8 * (r >> 2);    // n-octet 0..15
                bf16x8 v = *(const bf16x8*)&ep[tl * 128 + ((oo ^ (tl & 7)) << 3)];
                const int t = tb + tl;
                const int hh = hb + (oo >> 3);
                const int d8 = oo & 7;                      // dim-octet in head
                if (sec == 0) {
                    *(bf16x8*)&Qb[((size_t)(bbu * Hc + hh) * Tc + t) * HDc + d8 * 8] = v;
                } else {
                    // K global dim-XOR is octet-granular: fold into octet index
                    *(bf16x8*)&Kb[((size_t)(bbu * Hc + hh) * Tc + t) * HDc
                                  + ((d8 ^ (t & 7)) * 8)] = v;
                }
            }
        } else {
            // ---- V: scatter into LDS [dim][pos] (2B), store coalesced along pos ----
            _Float16* epv = (_Float16*)ep;
#pragma unroll
            for (int a = 0; a < 4; a++) {
                const int n0l = wn + a * 16 + qd * 4;
                const float4 bi = *(const float4*)&bias[tileN + n0l];
#pragma unroll
                for (int b = 0; b < 4; b++) {
                    const int ml = wm + b * 16 + lm;
                    const int u = ml & 31;
                    const int posA = (ml & ~31) + (((u & 15) >> 2) << 3)
                                     + ((u >> 4) << 2) + (u & 3);
                    const float vv[4] = {acc[a][b][0] + bi.x, acc[a][b][1] + bi.y,
                                         acc[a][b][2] + bi.z, acc[a][b][3] + bi.w};
#pragma unroll
                    for (int r = 0; r < 4; r++) {
                        const int dl = n0l + r;                 // local dim-row 0..127
                        const int pos = posA ^ ((dl & 7) << 3); // octet-granular XOR
                        epv[dl * 128 + pos] = (_Float16)vv[r];
                    }
                }
            }
            __syncthreads();
#pragma unroll
            for (int r = 0; r < 8; r++) {
                const int dl = (tid >> 3) + 32 * (r & 3);   // dim-row 0..127
                const int po = (tid & 7) + 8 * (r >> 2);    // pos-octet 0..15
                bf16x8 v = *(const bf16x8*)&epv[dl * 128 + po * 8];
                const int hh = hb + (dl >> 6);
                const int dim = dl & 63;
                *(bf16x8*)&Vb[((size_t)(bbu * Hc + hh) * HDc + dim) * Tc
                              + tb + po * 8] = v;
            }
        }
    } else {
#pragma unroll
        for (int a = 0; a < 4; a++) {
            const int n0 = tileN + wn + a * 16 + qd * 4;
            const float4 bi = *(const float4*)&bias[n0];
#pragma unroll
            for (int b = 0; b < 4; b++) {
                const int m = tileM + wm + b * 16 + lm;
                float4 o;
                o.x = acc[a][b][0] + bi.x;
                o.y = acc[a][b][1] + bi.y;
                o.z = acc[a][b][2] + bi.z;
                o.w = acc[a][b][3] + bi.w;
                *(float4*)&Cout[(size_t)m * N + n0] = o;
            }
        }
    }
}

// ---------------- flash attention, fixed-max softmax, depth-2 pipelined KV ----------------
// Bq=256/block (64 q/wave, qn=4). Bk=64 keys/tile, FOUR LDS buffers (64 KB).
// Per iter: stage tile kt+2, compute tile kt, counted vmcnt(4) (waits only tile
// kt+1's 4 loads; never drains to 0 until tail — T4), ONE s_barrier.
// Buffer reused 4 tiles later -> 2-barrier safety margin. Occupancy is
// GRID-limited (512 blocks = 2/CU), so LDS 64 KB costs nothing here.
// Row-sums via ones-MFMA. S^T C-layout: the CONCAT of two 16-key S^T fragments
// == B-operand of mfma_f32_16x16x32_f16 under V's permuted key order (posA
// interleave) -> PV + rowsum run on the full-rate K=32 op.
// (Round-9: register S-ahead pipeline spilled -> 147 us. Keep this form.)

__global__ __launch_bounds__(256, 2) void attn_kernel(
    const __hip_bfloat16* __restrict__ Qb, const __hip_bfloat16* __restrict__ Kb,
    const _Float16* __restrict__ Vh, __hip_bfloat16* __restrict__ AO)
{
    __shared__ __align__(16) __hip_bfloat16 sK[4][64 * 64];   // [key][dim^swz(key)]
    __shared__ __align__(16) _Float16 sV[4][64 * 64];         // [dim][perm-key^swz(dim)]
    const int tid = threadIdx.x, wave = tid >> 6, lane = tid & 63;
    const int qd = lane >> 4, lm = lane & 15;
    // XCD-aware mapping: block i -> XCD i%8; all 8 q-blocks of a bh on one XCD
    const int i = blockIdx.x;            // 512 blocks
    const int c = i & 7, j = i >> 3;     // j 0..63
    const int bh = c + 8 * (j >> 3);
    const int qblk = j & 7;
    const int q0 = qblk * 256 + wave * 64;

    const __hip_bfloat16* Qp = Qb + (size_t)bh * Tc * HDc;
    const __hip_bfloat16* Kp = Kb + (size_t)bh * Tc * HDc;
    const _Float16* Vp = Vh + (size_t)bh * HDc * Tc;

    bf16x8 qf[4][2];   // [qn][ks]: B-frag, lane: q=lm, k=ks*32+qd*8+j
#pragma unroll
    for (int qn = 0; qn < 4; qn++)
#pragma unroll
        for (int ks = 0; ks < 2; ks++)
            qf[qn][ks] = *(const bf16x8*)(Qp + (size_t)(q0 + qn * 16 + lm) * HDc
                                          + ks * 32 + qd * 8);

    f32x4 o[4][4];     // [qn][cb]: O^T, lane: q=lm, dim=cb*16+qd*4+r
    f32x4 lsum[4];     // [qn]: row-sum accumulator (all 4 regs identical)
#pragma unroll
    for (int qn = 0; qn < 4; qn++) {
#pragma unroll
        for (int cb = 0; cb < 4; cb++) o[qn][cb] = (f32x4){0.f, 0.f, 0.f, 0.f};
        lsum[qn] = (f32x4){0.f, 0.f, 0.f, 0.f};
    }
    const f16x8 one8 = {(_Float16)1.f, (_Float16)1.f, (_Float16)1.f, (_Float16)1.f,
                        (_Float16)1.f, (_Float16)1.f, (_Float16)1.f, (_Float16)1.f};

    const int swl = (lm & 7) << 3;

    // stage one 64-key tile (8 KB K + 8 KB V); 4 gld16 per wave
    auto stage = [&](int p, int k0) {
        const char* gK = (const char*)(Kp + (size_t)k0 * HDc);
#pragma unroll
        for (int jj = 0; jj < 2; jj++) {
            const int call = wave * 2 + jj;
            gld16(gK + call * 1024 + lane * 16,
                  (char*)&sK[p][0] + call * 1024 + lane * 16);
            const int dim = call * 8 + (lane >> 3);
            gld16((const char*)(Vp + (size_t)dim * Tc + k0 + (lane & 7) * 8),
                  (char*)&sV[p][0] + call * 1024 + lane * 16);
        }
    };

    constexpr int NT = Tc / 64;          // 32 tiles
    stage(0, 0);
    stage(1, 64);
    __builtin_amdgcn_s_waitcnt(0xF74);   // vmcnt(4): tile 0 landed (tile 1 in flight)
    __builtin_amdgcn_s_barrier();

    for (int kt = 0; kt < NT; kt++) {
        const int p = kt & 3;
        if (kt + 2 < NT) stage((kt + 2) & 3, (kt + 2) * 64);

        const __hip_bfloat16* bK = &sK[p][0];
        const _Float16* bV = &sV[p][0];

        // ---- S^T = K @ Q^T over 64 keys; P = exp2(S) straight away ----
        // pf8[qn][g] = concat of key-blocks 2g (elems 0-3) and 2g+1 (elems 4-7):
        // lane (qd,lm) holds keys {32g+4qd+0..3, 32g+16+4qd+0..3} — exactly V's
        // stored key order at positions 32g+8qd+{0..7}.
        f16x8 pf8[4][2];
#pragma unroll
        for (int g = 0; g < 2; g++) {
#pragma unroll
            for (int hh = 0; hh < 2; hh++) {
                const int krow = (2 * g + hh) * 16 + lm;
                bf16x8 kf0 = *(const bf16x8*)&bK[krow * 64 + ((0 + qd * 8) ^ swl)];
                bf16x8 kf1 = *(const bf16x8*)&bK[krow * 64 + ((32 + qd * 8) ^ swl)];
#pragma unroll
                for (int qn = 0; qn < 4; qn++) {
                    f32x4 s = (f32x4){0.f, 0.f, 0.f, 0.f};
                    s = __builtin_amdgcn_mfma_f32_16x16x32_bf16(kf0, qf[qn][0], s, 0, 0, 0);
                    s = __builtin_amdgcn_mfma_f32_16x16x32_bf16(kf1, qf[qn][1], s, 0, 0, 0);
                    auto lo = __builtin_amdgcn_cvt_pkrtz(EXP2F(s[0]), EXP2F(s[1]));
                    auto hi = __builtin_amdgcn_cvt_pkrtz(EXP2F(s[2]), EXP2F(s[3]));
                    pf8[qn][g][4 * hh + 0] = lo[0];
                    pf8[qn][g][4 * hh + 1] = lo[1];
                    pf8[qn][g][4 * hh + 2] = hi[0];
                    pf8[qn][g][4 * hh + 3] = hi[1];
                }
            }
        }

        // ---- row sums on the matrix pipe: lsum += 1 * P^T (K=32) ----
#pragma unroll
        for (int qn = 0; qn < 4; qn++)
#pragma unroll
            for (int g = 0; g < 2; g++)
                lsum[qn] = __builtin_amdgcn_mfma_f32_16x16x32_f16(
                    one8, pf8[qn][g], lsum[qn], 0, 0, 0);

        // ---- O^T += V^T @ P^T, register-direct, full-rate K=32 f16 MFMA ----
#pragma unroll
        for (int g = 0; g < 2; g++) {
#pragma unroll
            for (int cb = 0; cb < 4; cb++) {
                f16x8 v8 = *(const f16x8*)&bV[(cb * 16 + lm) * 64
                                              + ((g * 32 + qd * 8) ^ swl)];
#pragma unroll
                for (int qn = 0; qn < 4; qn++)
                    o[qn][cb] = __builtin_amdgcn_mfma_f32_16x16x32_f16(
                        v8, pf8[qn][g], o[qn][cb], 0, 0, 0);
            }
        }

        if (kt + 1 < NT) {
            if (kt + 2 < NT) __builtin_amdgcn_s_waitcnt(0xF74);  // vmcnt(4): tile kt+1 in
            else             __builtin_amdgcn_s_waitcnt(0xF70);  // vmcnt(0): drain tail
            __builtin_amdgcn_s_barrier();    // reads of p done + tile kt+1 visible
        }
    }

    const int b = bh >> 4, h = bh & 15;
#pragma unroll
    for (int qn = 0; qn < 4; qn++) {
        const float rinv = 1.f / lsum[qn][0];
        const int t = q0 + qn * 16 + lm;
#pragma unroll
        for (int cb = 0; cb < 4; cb++)
#pragma unroll
            for (int r = 0; r < 4; r++) {
                const int dim = cb * 16 + qd * 4 + r;
                AO[((size_t)b * Tc + t) * Dc + h * HDc + dim] =
                    (__hip_bfloat16)(o[qn][cb][r] * rinv);
            }
    }
}

// ---------------- launch ----------------

extern "C" void kernel_launch(void* const* d_in, const int* in_sizes, int n_in,
                              void* d_out, int out_size, void* d_ws, size_t ws_size,
                              hipStream_t stream)
{
    const float* x      = (const float*)d_in[0];
    const float* W_attn = (const float*)d_in[1];
    const float* b_attn = (const float*)d_in[2];
    const float* W_proj = (const float*)d_in[3];
    const float* b_proj = (const float*)d_in[4];
    float* out = (float*)d_out;

    char* w = (char*)d_ws;
    auto alloc = [&](size_t bytes) -> char* {
        char* p = w;
        w += (bytes + 255) & ~(size_t)255;
        return p;
    };
    __hip_bfloat16* xb  = (__hip_bfloat16*)alloc((size_t)Bc * Tc * Dc * 2);
    __hip_bfloat16* Wqt = (__hip_bfloat16*)alloc((size_t)3 * Dc * Dc * 2);
    __hip_bfloat16* Wpt = (__hip_bfloat16*)alloc((size_t)Dc * Dc * 2);
    __hip_bfloat16* Qb  = (__hip_bfloat16*)alloc((size_t)Bc * Hc * Tc * HDc * 2);
    __hip_bfloat16* Kb  = (__hip_bfloat16*)alloc((size_t)Bc * Hc * Tc * HDc * 2);
    _Float16*       Vh  = (_Float16*)alloc((size_t)Bc * Hc * Tc * HDc * 2);
    __hip_bfloat16* AO  = (__hip_bfloat16*)alloc((size_t)Bc * Tc * Dc * 2);
    float* sinT = (float*)alloc((size_t)Tc * 64 * 4);
    float* cosT = (float*)alloc((size_t)Tc * 64 * 4);

    const int M = Bc * Tc;  // 8192

    prep_kernel<<<dim3(3584), dim3(256), 0, stream>>>(
        (const float4*)x, (ushort4*)xb, W_attn, Wqt, W_proj, Wpt, sinT, cosT);

    gemm128<0><<<dim3(3 * Dc / 128, M / 128), dim3(256), 0, stream>>>(
        xb, Wqt, b_attn, M, 3 * Dc, Dc, sinT, cosT, Qb, Kb, Vh, nullptr);

    attn_kernel<<<dim3(512), dim3(256), 0, stream>>>(Qb, Kb, Vh, AO);

    gemm128<1><<<dim3(Dc / 128, M / 128), dim3(256), 0, stream>>>(
        AO, Wpt, b_proj, M, Dc, Dc, nullptr, nullptr, nullptr, nullptr, nullptr, out);
}

// Round 12
// 244.371 us; speedup vs baseline: 1.3855x; 1.0732x over previous
//
#include <hip/hip_runtime.h>
#include <hip/hip_bf16.h>
#include <stdint.h>

#define DEVI __device__ __forceinline__

using bf16x8 = __attribute__((ext_vector_type(8))) short;
using f32x4  = __attribute__((ext_vector_type(4))) float;
using f16x4  = __attribute__((ext_vector_type(4))) _Float16;
using f16x8  = __attribute__((ext_vector_type(8))) _Float16;

static constexpr int Bc = 4;
static constexpr int Tc = 2048;
static constexpr int Dc = 1024;
static constexpr int Hc = 16;
static constexpr int HDc = 64;
// 1/sqrt(512) * log2(e), folded into Q so softmax uses exp2 directly
#define QSCALE 0.06375788883274286f

#if __has_builtin(__builtin_amdgcn_exp2f)
#define EXP2F __builtin_amdgcn_exp2f
#else
#define EXP2F exp2f
#endif

typedef const unsigned int __attribute__((address_space(1)))* gas1_t;
typedef unsigned int __attribute__((address_space(3)))* las3_t;

DEVI void gld16(const void* g, void* l)
{
    __builtin_amdgcn_global_load_lds((gas1_t)(uintptr_t)g, (las3_t)(uintptr_t)l, 16, 0, 0);
}

// ---------------- fused prep kernel ----------------
// One launch, block-range partitioned (saves 3 kernel launch gaps):
//   blocks [0,2048):     x fp32 -> bf16 (64B/thread, block-strided)
//   blocks [2048,2816):  W_attn [K][N] fp32 -> Wqt [N][K] bf16 (64x64 tiles)
//   blocks [2816,3072):  W_proj -> Wpt
//   blocks [3072,3584):  RoPE sin/cos tables

DEVI void transpose_tile(const float* __restrict__ W, __hip_bfloat16* __restrict__ Wt,
                         int K, int N, int n0, int k0, float (*tile)[65], int tid)
{
    const int tx = tid & 15, ty = tid >> 4;   // 16 x 16
#pragma unroll
    for (int i2 = 0; i2 < 4; i2++) {
        const int k = ty + 16 * i2;
        float4 v = *(const float4*)&W[(size_t)(k0 + k) * N + n0 + tx * 4];
        tile[tx * 4 + 0][k] = v.x;
        tile[tx * 4 + 1][k] = v.y;
        tile[tx * 4 + 2][k] = v.z;
        tile[tx * 4 + 3][k] = v.w;
    }
    __syncthreads();
#pragma unroll
    for (int i2 = 0; i2 < 4; i2++) {
        const int n = ty + 16 * i2;
        union { __hip_bfloat16 h[4]; ushort4 u4; } cv;
#pragma unroll
        for (int c = 0; c < 4; c++)
            cv.h[c] = (__hip_bfloat16)tile[n][tx * 4 + c];
        *(ushort4*)&Wt[(size_t)(n0 + n) * K + k0 + tx * 4] = cv.u4;
    }
}

__global__ __launch_bounds__(256) void prep_kernel(
    const float4* __restrict__ x, ushort4* __restrict__ xb,
    const float* __restrict__ W_attn, __hip_bfloat16* __restrict__ Wqt,
    const float* __restrict__ W_proj, __hip_bfloat16* __restrict__ Wpt,
    float* __restrict__ sinT, float* __restrict__ cosT)
{
    __shared__ float tile[64][65];
    const int bid = blockIdx.x, tid = threadIdx.x;
    if (bid < 2048) {
        const int base = bid * 1024 + tid;
#pragma unroll
        for (int u = 0; u < 4; u++) {
            const int i = base + u * 256;
            float4 v = x[i];
            union { __hip_bfloat16 h[4]; ushort4 u4; } cv;
            cv.h[0] = __float2bfloat16(v.x);
            cv.h[1] = __float2bfloat16(v.y);
            cv.h[2] = __float2bfloat16(v.z);
            cv.h[3] = __float2bfloat16(v.w);
            xb[i] = cv.u4;
        }
    } else if (bid < 2816) {
        const int b2 = bid - 2048;                    // grid was (48, 16)
        transpose_tile(W_attn, Wqt, Dc, 3 * Dc, (b2 % 48) * 64, (b2 / 48) * 64, tile, tid);
    } else if (bid < 3072) {
        const int b3 = bid - 2816;                    // grid was (16, 16)
        transpose_tile(W_proj, Wpt, Dc, Dc, (b3 % 16) * 64, (b3 / 16) * 64, tile, tid);
    } else {
        const int i = (bid - 3072) * 256 + tid;       // Tc*64 total
        const int t = i >> 6, dim = i & 63;
        const int p = dim >> 1;
        float theta = powf(1000.f, -2.f * (float)(p + 1) / 64.f);
        float arg = (float)(t + 1) * theta;
        sinT[i] = sinf(arg);
        cosT[i] = cosf(arg);
    }
}

// ---------------- GEMM: 128x128 tile, TRANSPOSED C-orientation ----------------
// A-operand = weight rows (n), B-operand = x rows (m) -> D[n][m].
// K-loop: m97 structure — SINGLE-buffered LDS (32 KB -> ~4 blocks/CU), plain
// drain loop {stage -> vmcnt(0) -> barrier -> compute -> barrier}. Pipelining
// from implicit wave-level overlap across co-resident blocks (m114).
// LDS octet XOR-swizzle (pre-swizzled GLOBAL source + swizzled read; LDS linear,
// rule #21) kills the 16-way ds_read_b128 bank conflict.
// MODE 0 epilogue (round 11, verified): outputs bounced through the freed 32 KB
// LDS, stored COALESCED (full 128B rows per wave-instr). gemm0 dropped out of
// the top-5 dispatches after this change.
// MODE 1 epilogue (round 12): same bounce for the fp32 proj output — two
// 64-row passes (64x128x4B = 32 KB exact fit), owning waves ds_write swizzled,
// all threads store 2 full 512B rows per instr. Values bit-identical.

template <int MODE>
__global__ __launch_bounds__(256, 4) void gemm128(
    const __hip_bfloat16* __restrict__ A, const __hip_bfloat16* __restrict__ Bt,
    const float* __restrict__ bias, int M, int N, int K,
    const float* __restrict__ sinT, const float* __restrict__ cosT,
    __hip_bfloat16* __restrict__ Qb, __hip_bfloat16* __restrict__ Kb,
    _Float16* __restrict__ Vb, float* __restrict__ Cout)
{
    __shared__ __align__(16) __hip_bfloat16 smem[2][128 * 64];
    __hip_bfloat16* sA = smem[0];
    __hip_bfloat16* sB = smem[1];
    const int tid = threadIdx.x;
    const int wave = tid >> 6, lane = tid & 63;
    const int qd = lane >> 4, lm = lane & 15;
    const int wm = (wave >> 1) * 64, wn = (wave & 1) * 64;
    const int tileM = blockIdx.y * 128, tileN = blockIdx.x * 128;

    const int srow = tid >> 3;                      // 0..31 (staged row within chunk)
    const int socc = (tid & 7) ^ (srow & 7);        // swizzled source octet

    f32x4 acc[4][4];                    // [a: n-block][b: m-block]
#pragma unroll
    for (int i = 0; i < 4; i++)
#pragma unroll
        for (int j = 0; j < 4; j++)
            acc[i][j] = (f32x4){0.f, 0.f, 0.f, 0.f};

    // LDS[row][o] holds global octet o ^ (row&7); rows stay linear for gld16
    const __hip_bfloat16* pa = A + (size_t)(tileM + srow) * K + socc * 8;
    const __hip_bfloat16* pb = Bt + (size_t)(tileN + srow) * K + socc * 8;

    auto stageT = [&](int k0) {
#pragma unroll
        for (int it = 0; it < 4; it++) {
            gld16(pa + (size_t)(it * 32) * K + k0, &sA[it * 2048 + wave * 512]);
            gld16(pb + (size_t)(it * 32) * K + k0, &sB[it * 2048 + wave * 512]);
        }
    };

    const int swl = (lm & 7) << 3;      // read-side octet swizzle (row&7 == lm&7)
    const int nk = K / 64;
    for (int kt = 0; kt < nk; kt++) {
        stageT(kt * 64);
        __builtin_amdgcn_s_waitcnt(0xF70);       // vmcnt(0): tile kt landed
        __builtin_amdgcn_s_barrier();            // all waves' loads landed

#pragma unroll
        for (int ks = 0; ks < 2; ks++) {
            bf16x8 wf[4], xf[4];
#pragma unroll
            for (int a = 0; a < 4; a++)
                wf[a] = *(const bf16x8*)&sB[(wn + a * 16 + lm) * 64
                                            + ((ks * 32 + qd * 8) ^ swl)];
#pragma unroll
            for (int b = 0; b < 4; b++)
                xf[b] = *(const bf16x8*)&sA[(wm + b * 16 + lm) * 64
                                            + ((ks * 32 + qd * 8) ^ swl)];
#pragma unroll
            for (int a = 0; a < 4; a++)
#pragma unroll
                for (int b = 0; b < 4; b++)
                    acc[a][b] = __builtin_amdgcn_mfma_f32_16x16x32_bf16(
                        wf[a], xf[b], acc[a][b], 0, 0, 0);
        }
        if (kt + 1 < nk)
            __builtin_amdgcn_s_barrier();        // reads done before next overwrite
    }

    if constexpr (MODE == 0) {
        __syncthreads();                          // K-loop LDS now reusable
        __hip_bfloat16* ep = &smem[0][0];         // 128x128 bounce tile (32 KB)
        const int sec = tileN >> 10;              // q/k/v section, block-uniform
        const int hb = (tileN & 1023) >> 6;       // first head of this tile
        const int bbu = tileM >> 11;              // batch, block-uniform
        const int tb = tileM & (Tc - 1);          // t-base, 128-aligned

        if (sec < 2) {
            // ---- write side: RoPE in-reg, pack 4 dims, swizzled b64 LDS write ----
#pragma unroll
            for (int a = 0; a < 4; a++) {
                const int n0l = wn + a * 16 + qd * 4;   // local n, 0..127
                const int dim0 = n0l & 63;              // dim within head
                const float4 bi = *(const float4*)&bias[tileN + n0l];
#pragma unroll
                for (int b = 0; b < 4; b++) {
                    const int ml = wm + b * 16 + lm;    // local m, 0..127
                    const int t = tb + ml;
                    const float v0 = acc[a][b][0] + bi.x;
                    const float v1 = acc[a][b][1] + bi.y;
                    const float v2 = acc[a][b][2] + bi.z;
                    const float v3 = acc[a][b][3] + bi.w;
                    const float4 sn = *(const float4*)&sinT[t * 64 + dim0];
                    const float4 cs = *(const float4*)&cosT[t * 64 + dim0];
                    float o0 = v0 * cs.x - v1 * sn.x;   // even dim
                    float o1 = v1 * cs.y + v0 * sn.y;   // odd dim
                    float o2 = v2 * cs.z - v3 * sn.z;
                    float o3 = v3 * cs.w + v2 * sn.w;
                    if (sec == 0) {
                        o0 *= QSCALE; o1 *= QSCALE; o2 *= QSCALE; o3 *= QSCALE;
                    }
                    union { __hip_bfloat16 hx[4]; ushort4 u4; } cv;
                    cv.hx[0] = (__hip_bfloat16)o0;
                    cv.hx[1] = (__hip_bfloat16)o1;
                    cv.hx[2] = (__hip_bfloat16)o2;
                    cv.hx[3] = (__hip_bfloat16)o3;
                    // bank-swizzle: XOR octet index by ml&7 (4-el granule safe)
                    *(ushort4*)&ep[ml * 128 + (n0l ^ ((ml & 7) << 3))] = cv.u4;
                }
            }
            __syncthreads();
            // ---- readback + coalesced store: lanes 0-7 = one t-row's octets ----
#pragma unroll
            for (int r = 0; r < 8; r++) {
                const int tl = (tid >> 3) + 32 * (r & 3);   // t-row 0..127
                const int oo = (tid & 7) + 8 * (r >> 2);    // n-octet 0..15
                bf16x8 v = *(const bf16x8*)&ep[tl * 128 + ((oo ^ (tl & 7)) << 3)];
                const int t = tb + tl;
                const int hh = hb + (oo >> 3);
                const int d8 = oo & 7;                      // dim-octet in head
                if (sec == 0) {
                    *(bf16x8*)&Qb[((size_t)(bbu * Hc + hh) * Tc + t) * HDc + d8 * 8] = v;
                } else {
                    // K global dim-XOR is octet-granular: fold into octet index
                    *(bf16x8*)&Kb[((size_t)(bbu * Hc + hh) * Tc + t) * HDc
                                  + ((d8 ^ (t & 7)) * 8)] = v;
                }
            }
        } else {
            // ---- V: scatter into LDS [dim][pos] (2B), store coalesced along pos ----
            _Float16* epv = (_Float16*)ep;
#pragma unroll
            for (int a = 0; a < 4; a++) {
                const int n0l = wn + a * 16 + qd * 4;
                const float4 bi = *(const float4*)&bias[tileN + n0l];
#pragma unroll
                for (int b = 0; b < 4; b++) {
                    const int ml = wm + b * 16 + lm;
                    const int u = ml & 31;
                    const int posA = (ml & ~31) + (((u & 15) >> 2) << 3)
                                     + ((u >> 4) << 2) + (u & 3);
                    const float vv[4] = {acc[a][b][0] + bi.x, acc[a][b][1] + bi.y,
                                         acc[a][b][2] + bi.z, acc[a][b][3] + bi.w};
#pragma unroll
                    for (int r = 0; r < 4; r++) {
                        const int dl = n0l + r;                 // local dim-row 0..127
                        const int pos = posA ^ ((dl & 7) << 3); // octet-granular XOR
                        epv[dl * 128 + pos] = (_Float16)vv[r];
                    }
                }
            }
            __syncthreads();
#pragma unroll
            for (int r = 0; r < 8; r++) {
                const int dl = (tid >> 3) + 32 * (r & 3);   // dim-row 0..127
                const int po = (tid & 7) + 8 * (r >> 2);    // pos-octet 0..15
                bf16x8 v = *(const bf16x8*)&epv[dl * 128 + po * 8];
                const int hh = hb + (dl >> 6);
                const int dim = dl & 63;
                *(bf16x8*)&Vb[((size_t)(bbu * Hc + hh) * HDc + dim) * Tc
                              + tb + po * 8] = v;
            }
        }
    } else {
        // ---- proj epilogue: LDS-bounced coalesced fp32 stores, 2 x 64-row passes ----
        __syncthreads();                          // K-loop LDS now reusable
        float* epf = (float*)&smem[0][0];         // 64 x 128 fp32 = 32 KB exact
#pragma unroll
        for (int pass = 0; pass < 2; pass++) {
            if ((wave >> 1) == pass) {            // these waves own rows [64p, 64p+64)
#pragma unroll
                for (int a = 0; a < 4; a++) {
                    const int n0l = wn + a * 16 + qd * 4;      // local n, 0..127
                    const float4 bi = *(const float4*)&bias[tileN + n0l];
#pragma unroll
                    for (int b = 0; b < 4; b++) {
                        const int rl = b * 16 + lm;            // row 0..63 in pass
                        float4 o;
                        o.x = acc[a][b][0] + bi.x;
                        o.y = acc[a][b][1] + bi.y;
                        o.z = acc[a][b][2] + bi.z;
                        o.w = acc[a][b][3] + bi.w;
                        // float4-index swizzle by row (involution on readback)
                        const int f4 = (n0l >> 2) ^ ((rl & 7) << 2);
                        *(float4*)&epf[rl * 128 + f4 * 4] = o;
                    }
                }
            }
            __syncthreads();
            // readback: 2048 float4s; each wave-instr = 2 full 512B rows
#pragma unroll
            for (int r = 0; r < 8; r++) {
                const int idx = r * 256 + tid;                 // 0..2047
                const int rl = idx >> 5;                       // row 0..63
                const int f4 = idx & 31;
                float4 v = *(const float4*)&epf[rl * 128
                                                + ((f4 ^ ((rl & 7) << 2)) * 4)];
                const int m = tileM + pass * 64 + rl;
                *(float4*)&Cout[(size_t)m * N + tileN + f4 * 4] = v;
            }
            __syncthreads();                      // pass-0 LDS reusable for pass 1
        }
    }
}

// ---------------- flash attention, fixed-max softmax, depth-2 pipelined KV ----------------
// Bq=256/block (64 q/wave, qn=4). Bk=64 keys/tile, FOUR LDS buffers (64 KB).
// Per iter: stage tile kt+2, compute tile kt, counted vmcnt(4) (waits only tile
// kt+1's 4 loads; never drains to 0 until tail — T4), ONE s_barrier.
// Buffer reused 4 tiles later -> 2-barrier safety margin. Occupancy is
// GRID-limited (512 blocks = 2/CU), so LDS 64 KB costs nothing here.
// Row-sums via ones-MFMA. S^T C-layout: the CONCAT of two 16-key S^T fragments
// == B-operand of mfma_f32_16x16x32_f16 under V's permuted key order (posA
// interleave) -> PV + rowsum run on the full-rate K=32 op.
// Status (round 11 counters): MfmaUtil 46 + VALUBusy 42 = 88% combined pipe
// busy, conflicts 0, WRITE_SIZE at ideal. Structural floor is max(33,30) us
// with perfect cross-wave overlap; all routes there measured-blocked (rounds
// 4 and 9). Keep this form.

__global__ __launch_bounds__(256, 2) void attn_kernel(
    const __hip_bfloat16* __restrict__ Qb, const __hip_bfloat16* __restrict__ Kb,
    const _Float16* __restrict__ Vh, __hip_bfloat16* __restrict__ AO)
{
    __shared__ __align__(16) __hip_bfloat16 sK[4][64 * 64];   // [key][dim^swz(key)]
    __shared__ __align__(16) _Float16 sV[4][64 * 64];         // [dim][perm-key^swz(dim)]
    const int tid = threadIdx.x, wave = tid >> 6, lane = tid & 63;
    const int qd = lane >> 4, lm = lane & 15;
    // XCD-aware mapping: block i -> XCD i%8; all 8 q-blocks of a bh on one XCD
    const int i = blockIdx.x;            // 512 blocks
    const int c = i & 7, j = i >> 3;     // j 0..63
    const int bh = c + 8 * (j >> 3);
    const int qblk = j & 7;
    const int q0 = qblk * 256 + wave * 64;

    const __hip_bfloat16* Qp = Qb + (size_t)bh * Tc * HDc;
    const __hip_bfloat16* Kp = Kb + (size_t)bh * Tc * HDc;
    const _Float16* Vp = Vh + (size_t)bh * HDc * Tc;

    bf16x8 qf[4][2];   // [qn][ks]: B-frag, lane: q=lm, k=ks*32+qd*8+j
#pragma unroll
    for (int qn = 0; qn < 4; qn++)
#pragma unroll
        for (int ks = 0; ks < 2; ks++)
            qf[qn][ks] = *(const bf16x8*)(Qp + (size_t)(q0 + qn * 16 + lm) * HDc
                                          + ks * 32 + qd * 8);

    f32x4 o[4][4];     // [qn][cb]: O^T, lane: q=lm, dim=cb*16+qd*4+r
    f32x4 lsum[4];     // [qn]: row-sum accumulator (all 4 regs identical)
#pragma unroll
    for (int qn = 0; qn < 4; qn++) {
#pragma unroll
        for (int cb = 0; cb < 4; cb++) o[qn][cb] = (f32x4){0.f, 0.f, 0.f, 0.f};
        lsum[qn] = (f32x4){0.f, 0.f, 0.f, 0.f};
    }
    const f16x8 one8 = {(_Float16)1.f, (_Float16)1.f, (_Float16)1.f, (_Float16)1.f,
                        (_Float16)1.f, (_Float16)1.f, (_Float16)1.f, (_Float16)1.f};

    const int swl = (lm & 7) << 3;

    // stage one 64-key tile (8 KB K + 8 KB V); 4 gld16 per wave
    auto stage = [&](int p, int k0) {
        const char* gK = (const char*)(Kp + (size_t)k0 * HDc);
#pragma unroll
        for (int jj = 0; jj < 2; jj++) {
            const int call = wave * 2 + jj;
            gld16(gK + call * 1024 + lane * 16,
                  (char*)&sK[p][0] + call * 1024 + lane * 16);
            const int dim = call * 8 + (lane >> 3);
            gld16((const char*)(Vp + (size_t)dim * Tc + k0 + (lane & 7) * 8),
                  (char*)&sV[p][0] + call * 1024 + lane * 16);
        }
    };

    constexpr int NT = Tc / 64;          // 32 tiles
    stage(0, 0);
    stage(1, 64);
    __builtin_amdgcn_s_waitcnt(0xF74);   // vmcnt(4): tile 0 landed (tile 1 in flight)
    __builtin_amdgcn_s_barrier();

    for (int kt = 0; kt < NT; kt++) {
        const int p = kt & 3;
        if (kt + 2 < NT) stage((kt + 2) & 3, (kt + 2) * 64);

        const __hip_bfloat16* bK = &sK[p][0];
        const _Float16* bV = &sV[p][0];

        // ---- S^T = K @ Q^T over 64 keys; P = exp2(S) straight away ----
        // pf8[qn][g] = concat of key-blocks 2g (elems 0-3) and 2g+1 (elems 4-7):
        // lane (qd,lm) holds keys {32g+4qd+0..3, 32g+16+4qd+0..3} — exactly V's
        // stored key order at positions 32g+8qd+{0..7}.
        f16x8 pf8[4][2];
#pragma unroll
        for (int g = 0; g < 2; g++) {
#pragma unroll
            for (int hh = 0; hh < 2; hh++) {
                const int krow = (2 * g + hh) * 16 + lm;
                bf16x8 kf0 = *(const bf16x8*)&bK[krow * 64 + ((0 + qd * 8) ^ swl)];
                bf16x8 kf1 = *(const bf16x8*)&bK[krow * 64 + ((32 + qd * 8) ^ swl)];
#pragma unroll
                for (int qn = 0; qn < 4; qn++) {
                    f32x4 s = (f32x4){0.f, 0.f, 0.f, 0.f};
                    s = __builtin_amdgcn_mfma_f32_16x16x32_bf16(kf0, qf[qn][0], s, 0, 0, 0);
                    s = __builtin_amdgcn_mfma_f32_16x16x32_bf16(kf1, qf[qn][1], s, 0, 0, 0);
                    auto lo = __builtin_amdgcn_cvt_pkrtz(EXP2F(s[0]), EXP2F(s[1]));
                    auto hi = __builtin_amdgcn_cvt_pkrtz(EXP2F(s[2]), EXP2F(s[3]));
                    pf8[qn][g][4 * hh + 0] = lo[0];
                    pf8[qn][g][4 * hh + 1] = lo[1];
                    pf8[qn][g][4 * hh + 2] = hi[0];
                    pf8[qn][g][4 * hh + 3] = hi[1];
                }
            }
        }

        // ---- row sums on the matrix pipe: lsum += 1 * P^T (K=32) ----
#pragma unroll
        for (int qn = 0; qn < 4; qn++)
#pragma unroll
            for (int g = 0; g < 2; g++)
                lsum[qn] = __builtin_amdgcn_mfma_f32_16x16x32_f16(
                    one8, pf8[qn][g], lsum[qn], 0, 0, 0);

        // ---- O^T += V^T @ P^T, register-direct, full-rate K=32 f16 MFMA ----
#pragma unroll
        for (int g = 0; g < 2; g++) {
#pragma unroll
            for (int cb = 0; cb < 4; cb++) {
                f16x8 v8 = *(const f16x8*)&bV[(cb * 16 + lm) * 64
                                              + ((g * 32 + qd * 8) ^ swl)];
#pragma unroll
                for (int qn = 0; qn < 4; qn++)
                    o[qn][cb] = __builtin_amdgcn_mfma_f32_16x16x32_f16(
                        v8, pf8[qn][g], o[qn][cb], 0, 0, 0);
            }
        }

        if (kt + 1 < NT) {
            if (kt + 2 < NT) __builtin_amdgcn_s_waitcnt(0xF74);  // vmcnt(4): tile kt+1 in
            else             __builtin_amdgcn_s_waitcnt(0xF70);  // vmcnt(0): drain tail
            __builtin_amdgcn_s_barrier();    // reads of p done + tile kt+1 visible
        }
    }

    const int b = bh >> 4, h = bh & 15;
#pragma unroll
    for (int qn = 0; qn < 4; qn++) {
        const float rinv = 1.f / lsum[qn][0];
        const int t = q0 + qn * 16 + lm;
#pragma unroll
        for (int cb = 0; cb < 4; cb++)
#pragma unroll
            for (int r = 0; r < 4; r++) {
                const int dim = cb * 16 + qd * 4 + r;
                AO[((size_t)b * Tc + t) * Dc + h * HDc + dim] =
                    (__hip_bfloat16)(o[qn][cb][r] * rinv);
            }
    }
}

// ---------------- launch ----------------

extern "C" void kernel_launch(void* const* d_in, const int* in_sizes, int n_in,
                              void* d_out, int out_size, void* d_ws, size_t ws_size,
                              hipStream_t stream)
{
    const float* x      = (const float*)d_in[0];
    const float* W_attn = (const float*)d_in[1];
    const float* b_attn = (const float*)d_in[2];
    const float* W_proj = (const float*)d_in[3];
    const float* b_proj = (const float*)d_in[4];
    float* out = (float*)d_out;

    char* w = (char*)d_ws;
    auto alloc = [&](size_t bytes) -> char* {
        char* p = w;
        w += (bytes + 255) & ~(size_t)255;
        return p;
    };
    __hip_bfloat16* xb  = (__hip_bfloat16*)alloc((size_t)Bc * Tc * Dc * 2);
    __hip_bfloat16* Wqt = (__hip_bfloat16*)alloc((size_t)3 * Dc * Dc * 2);
    __hip_bfloat16* Wpt = (__hip_bfloat16*)alloc((size_t)Dc * Dc * 2);
    __hip_bfloat16* Qb  = (__hip_bfloat16*)alloc((size_t)Bc * Hc * Tc * HDc * 2);
    __hip_bfloat16* Kb  = (__hip_bfloat16*)alloc((size_t)Bc * Hc * Tc * HDc * 2);
    _Float16*       Vh  = (_Float16*)alloc((size_t)Bc * Hc * Tc * HDc * 2);
    __hip_bfloat16* AO  = (__hip_bfloat16*)alloc((size_t)Bc * Tc * Dc * 2);
    float* sinT = (float*)alloc((size_t)Tc * 64 * 4);
    float* cosT = (float*)alloc((size_t)Tc * 64 * 4);

    const int M = Bc * Tc;  // 8192

    prep_kernel<<<dim3(3584), dim3(256), 0, stream>>>(
        (const float4*)x, (ushort4*)xb, W_attn, Wqt, W_proj, Wpt, sinT, cosT);

    gemm128<0><<<dim3(3 * Dc / 128, M / 128), dim3(256), 0, stream>>>(
        xb, Wqt, b_attn, M, 3 * Dc, Dc, sinT, cosT, Qb, Kb, Vh, nullptr);

    attn_kernel<<<dim3(512), dim3(256), 0, stream>>>(Qb, Kb, Vh, AO);

    gemm128<1><<<dim3(Dc / 128, M / 128), dim3(256), 0, stream>>>(
        AO, Wpt, b_proj, M, Dc, Dc, nullptr, nullptr, nullptr, nullptr, nullptr, out);
}